// Round 1
// baseline (2896.025 us; speedup 1.0000x reference)
//
#include <hip/hip_runtime.h>
#include <math.h>

#define VOCAB 32000
#define EMB   256
#define TSEQ  1024
#define NROWS 4096
#define VT_PER (VOCAB/256)   // 125

// ---------------- embed: x = tok_table[idx] + pos_table[t] ----------------
__global__ __launch_bounds__(256) void k_embed(const int* __restrict__ idx,
                                               const float* __restrict__ tok,
                                               const float* __restrict__ pos,
                                               float* __restrict__ x) {
    int row = blockIdx.x;            // 0..4095
    int t = row & (TSEQ - 1);
    int token = idx[row];
    int e = threadIdx.x;             // 256 threads
    x[row * EMB + e] = tok[token * EMB + e] + pos[t * EMB + e];
}

// ---------------- qkv: C = x[4096,256] @ W[256,256], z selects q/k/v ----------------
__global__ __launch_bounds__(256) void k_qkv(const float* __restrict__ x,
                                             const float* __restrict__ Wq,
                                             const float* __restrict__ Wk,
                                             const float* __restrict__ Wv,
                                             float* __restrict__ q,
                                             float* __restrict__ k,
                                             float* __restrict__ v) {
    const float* W; float* out;
    if (blockIdx.z == 0)      { W = Wq; out = q; }
    else if (blockIdx.z == 1) { W = Wk; out = k; }
    else                      { W = Wv; out = v; }

    __shared__ float As[16][68];   // A^T tile, padded (272B row: 16B-aligned, conflict-light)
    __shared__ float Bs[16][64];

    int tid = threadIdx.x;
    int tx = tid & 15, ty = tid >> 4;
    int m0 = blockIdx.x * 64, n0 = blockIdx.y * 64;

    float acc[4][4] = {};
    for (int k0 = 0; k0 < EMB; k0 += 16) {
        #pragma unroll
        for (int i = 0; i < 4; ++i) {
            int lin = tid + i * 256;            // 0..1023
            int mm = lin >> 4, kk = lin & 15;
            As[kk][mm] = x[(m0 + mm) * EMB + k0 + kk];
        }
        #pragma unroll
        for (int i = 0; i < 4; ++i) {
            int lin = tid + i * 256;
            int kk = lin >> 6, nn = lin & 63;
            Bs[kk][nn] = W[(k0 + kk) * EMB + n0 + nn];
        }
        __syncthreads();
        #pragma unroll
        for (int kk = 0; kk < 16; ++kk) {
            float4 a4 = *(const float4*)&As[kk][ty * 4];
            float4 b4 = *(const float4*)&Bs[kk][tx * 4];
            float av[4] = {a4.x, a4.y, a4.z, a4.w};
            float bv[4] = {b4.x, b4.y, b4.z, b4.w};
            #pragma unroll
            for (int i = 0; i < 4; ++i)
                #pragma unroll
                for (int j = 0; j < 4; ++j)
                    acc[i][j] = fmaf(av[i], bv[j], acc[i][j]);
        }
        __syncthreads();
    }
    #pragma unroll
    for (int i = 0; i < 4; ++i) {
        float4 o4 = make_float4(acc[i][0], acc[i][1], acc[i][2], acc[i][3]);
        *(float4*)&out[(size_t)(m0 + ty * 4 + i) * EMB + n0 + tx * 4] = o4;
    }
}

// ---------------- flash attention: causal, scale 1/16 ----------------
#define QB 16
#define KB 16
__global__ __launch_bounds__(256) void k_attn(const float* __restrict__ q,
                                              const float* __restrict__ k,
                                              const float* __restrict__ v,
                                              float* __restrict__ o) {
    int b = blockIdx.y, qt = blockIdx.x;     // qt: 0..63
    int tid = threadIdx.x;
    __shared__ float q_s[QB][260];           // pad: 1040B rows (16B-aligned)
    __shared__ float k_s[KB][260];
    __shared__ float v_s[KB][EMB];
    __shared__ float p_s[QB][KB];
    __shared__ float mrow[QB], lrow[QB], arow[QB];

    const float* qb = q + (size_t)(b * TSEQ + qt * QB) * EMB;
    for (int i = tid; i < QB * EMB / 4; i += 256) {
        float4 t4 = ((const float4*)qb)[i];
        *(float4*)&q_s[i >> 6][(i & 63) * 4] = t4;
    }
    if (tid < QB) { mrow[tid] = -1e30f; lrow[tid] = 0.f; }
    float acc[QB];
    #pragma unroll
    for (int i = 0; i < QB; ++i) acc[i] = 0.f;
    int qi = tid >> 4, si = tid & 15;
    int e = tid;                              // PV column owner
    __syncthreads();

    for (int st = 0; st <= qt; ++st) {
        const float* kb = k + (size_t)(b * TSEQ + st * KB) * EMB;
        const float* vb = v + (size_t)(b * TSEQ + st * KB) * EMB;
        for (int i = tid; i < KB * EMB / 4; i += 256) {
            float4 k4 = ((const float4*)kb)[i];
            float4 v4 = ((const float4*)vb)[i];
            *(float4*)&k_s[i >> 6][(i & 63) * 4] = k4;
            *(float4*)&v_s[i >> 6][(i & 63) * 4] = v4;
        }
        __syncthreads();

        // scores: thread (qi, si)
        float s = 0.f;
        #pragma unroll 8
        for (int c = 0; c < EMB; c += 4) {
            float4 qv = *(const float4*)&q_s[qi][c];
            float4 kv = *(const float4*)&k_s[si][c];
            s = fmaf(qv.x, kv.x, s);
            s = fmaf(qv.y, kv.y, s);
            s = fmaf(qv.z, kv.z, s);
            s = fmaf(qv.w, kv.w, s);
        }
        s *= 0.0625f;                               // 256^-0.5
        if (st == qt && si > qi) s = -1e30f;        // causal mask (diagonal tile)

        float mt = s;
        #pragma unroll
        for (int off = 8; off; off >>= 1)
            mt = fmaxf(mt, __shfl_xor(mt, off, 16));
        float mo = mrow[qi];                        // same-wave group: race-free
        float mn = fmaxf(mo, mt);
        float p = __expf(s - mn);
        float lt = p;
        #pragma unroll
        for (int off = 8; off; off >>= 1)
            lt += __shfl_xor(lt, off, 16);
        p_s[qi][si] = p;
        if (si == 0) {
            float a = __expf(mo - mn);
            arow[qi] = a;
            mrow[qi] = mn;
            lrow[qi] = lrow[qi] * a + lt;
        }
        __syncthreads();

        // PV: thread = column e
        #pragma unroll
        for (int r = 0; r < QB; ++r) {
            float a = arow[r];
            float sum = 0.f;
            #pragma unroll
            for (int ss = 0; ss < KB; ++ss)
                sum = fmaf(p_s[r][ss], v_s[ss][e], sum);
            acc[r] = acc[r] * a + sum;
        }
        __syncthreads();
    }

    float* ob = o + (size_t)(b * TSEQ + qt * QB) * EMB;
    #pragma unroll
    for (int r = 0; r < QB; ++r)
        ob[r * EMB + e] = acc[r] / lrow[r];
}

// ---------------- logits + fused log-softmax NLL ----------------
#define IT 8
__global__ __launch_bounds__(256) void k_logits(const float* __restrict__ xo,
                                                const float* __restrict__ lmW,
                                                const float* __restrict__ lmb,
                                                const int* __restrict__ tgt,
                                                float* __restrict__ logits,
                                                float* __restrict__ loss) {
    int row0 = blockIdx.x * IT;
    int tid = threadIdx.x;
    const float* xr = xo + (size_t)row0 * EMB;   // wave-uniform -> s_load

    __shared__ float tl_s[IT];
    __shared__ float rm[IT][4], rs[IT][4];

    int tv[IT];
    #pragma unroll
    for (int i = 0; i < IT; ++i) tv[i] = tgt[row0 + i];
    float m[IT], sum[IT];
    #pragma unroll
    for (int i = 0; i < IT; ++i) { m[i] = -1e30f; sum[i] = 0.f; }

    for (int vt = 0; vt < VT_PER; ++vt) {
        int vcol = vt * 256 + tid;
        float bias = lmb[vcol];
        float acc[IT];
        #pragma unroll
        for (int i = 0; i < IT; ++i) acc[i] = bias;
        const float* wp = lmW + vcol;
        #pragma unroll 8
        for (int e = 0; e < EMB; ++e) {
            float w = wp[e * VOCAB];
            #pragma unroll
            for (int i = 0; i < IT; ++i)
                acc[i] = fmaf(xr[i * EMB + e], w, acc[i]);
        }
        #pragma unroll
        for (int i = 0; i < IT; ++i) {
            logits[(size_t)(row0 + i) * VOCAB + vcol] = acc[i];
            if (vcol == tv[i]) tl_s[i] = acc[i];
            float mn = fmaxf(m[i], acc[i]);
            sum[i] = sum[i] * __expf(m[i] - mn) + __expf(acc[i] - mn);
            m[i] = mn;
        }
    }

    // wave-level (m, sum) combine
    #pragma unroll
    for (int i = 0; i < IT; ++i) {
        #pragma unroll
        for (int off = 1; off < 64; off <<= 1) {
            float mo = __shfl_xor(m[i], off, 64);
            float so = __shfl_xor(sum[i], off, 64);
            float mn = fmaxf(m[i], mo);
            sum[i] = sum[i] * __expf(m[i] - mn) + so * __expf(mo - mn);
            m[i] = mn;
        }
    }
    int wave = tid >> 6, lane = tid & 63;
    if (lane == 0) {
        #pragma unroll
        for (int i = 0; i < IT; ++i) { rm[i][wave] = m[i]; rs[i][wave] = sum[i]; }
    }
    __syncthreads();
    if (tid == 0) {
        float total = 0.f;
        #pragma unroll
        for (int i = 0; i < IT; ++i) {
            float M = rm[i][0], S = rs[i][0];
            #pragma unroll
            for (int w = 1; w < 4; ++w) {
                float mo2 = rm[i][w], so2 = rs[i][w];
                float mn = fmaxf(M, mo2);
                S = S * __expf(M - mn) + so2 * __expf(mo2 - mn);
                M = mn;
            }
            total += (M + __logf(S)) - tl_s[i];   // -logp[tgt]
        }
        atomicAdd(loss, total * (1.0f / 4096.0f));
    }
}

extern "C" void kernel_launch(void* const* d_in, const int* in_sizes, int n_in,
                              void* d_out, int out_size, void* d_ws, size_t ws_size,
                              hipStream_t stream) {
    (void)in_sizes; (void)n_in; (void)ws_size;
    const int*   idx     = (const int*)d_in[0];
    const int*   targets = (const int*)d_in[1];
    const float* tok     = (const float*)d_in[2];
    const float* pos     = (const float*)d_in[3];
    const float* Wk      = (const float*)d_in[4];   // NOTE: Wk before Wq in input order
    const float* Wq      = (const float*)d_in[5];
    const float* Wv      = (const float*)d_in[6];
    const float* lmW     = (const float*)d_in[7];
    const float* lmb     = (const float*)d_in[8];

    float* logits = (float*)d_out;
    float* loss   = logits + (size_t)out_size - 1;  // last element = scalar loss

    float* ws = (float*)d_ws;                       // 5 * 1M floats = 20 MB
    float* x  = ws;
    float* q  = ws + (1u << 20);
    float* k  = ws + 2u * (1u << 20);
    float* v  = ws + 3u * (1u << 20);
    float* ao = ws + 4u * (1u << 20);

    k_embed<<<NROWS, 256, 0, stream>>>(idx, tok, pos, x);
    k_qkv<<<dim3(NROWS / 64, EMB / 64, 3), 256, 0, stream>>>(x, Wq, Wk, Wv, q, k, v);
    k_attn<<<dim3(TSEQ / QB, 4), 256, 0, stream>>>(q, k, v, ao);
    hipMemsetAsync(loss, 0, sizeof(float), stream);
    k_logits<<<NROWS / IT, 256, 0, stream>>>(ao, lmW, lmb, targets, logits, loss);
}

// Round 2
// 673.993 us; speedup vs baseline: 4.2968x; 4.2968x over previous
//
#include <hip/hip_runtime.h>
#include <hip/hip_bf16.h>
#include <math.h>

#define VOCAB 32000
#define EMB   256
#define TSEQ  1024
#define NROWS 4096

typedef __attribute__((ext_vector_type(8))) short short8;
typedef __attribute__((ext_vector_type(4))) float f32x4;

// ---------------- embed: x = tok_table[idx] + pos_table[t] ----------------
__global__ __launch_bounds__(256) void k_embed(const int* __restrict__ idx,
                                               const float* __restrict__ tok,
                                               const float* __restrict__ pos,
                                               float* __restrict__ x) {
    int row = blockIdx.x;
    int t = row & (TSEQ - 1);
    int token = idx[row];
    int e = threadIdx.x;
    x[row * EMB + e] = tok[token * EMB + e] + pos[t * EMB + e];
}

// ---------------- qkv: C = x[4096,256] @ W[256,256] ----------------
__global__ __launch_bounds__(256) void k_qkv(const float* __restrict__ x,
                                             const float* __restrict__ Wq,
                                             const float* __restrict__ Wk,
                                             const float* __restrict__ Wv,
                                             float* __restrict__ q,
                                             float* __restrict__ k,
                                             float* __restrict__ v) {
    const float* W; float* out;
    if (blockIdx.z == 0)      { W = Wq; out = q; }
    else if (blockIdx.z == 1) { W = Wk; out = k; }
    else                      { W = Wv; out = v; }

    __shared__ float As[16][68];
    __shared__ float Bs[16][64];

    int tid = threadIdx.x;
    int tx = tid & 15, ty = tid >> 4;
    int m0 = blockIdx.x * 64, n0 = blockIdx.y * 64;

    float acc[4][4] = {};
    for (int k0 = 0; k0 < EMB; k0 += 16) {
        #pragma unroll
        for (int i = 0; i < 4; ++i) {
            int lin = tid + i * 256;
            int mm = lin >> 4, kk = lin & 15;
            As[kk][mm] = x[(m0 + mm) * EMB + k0 + kk];
        }
        #pragma unroll
        for (int i = 0; i < 4; ++i) {
            int lin = tid + i * 256;
            int kk = lin >> 6, nn = lin & 63;
            Bs[kk][nn] = W[(k0 + kk) * EMB + n0 + nn];
        }
        __syncthreads();
        #pragma unroll
        for (int kk = 0; kk < 16; ++kk) {
            float4 a4 = *(const float4*)&As[kk][ty * 4];
            float4 b4 = *(const float4*)&Bs[kk][tx * 4];
            float av[4] = {a4.x, a4.y, a4.z, a4.w};
            float bv[4] = {b4.x, b4.y, b4.z, b4.w};
            #pragma unroll
            for (int i = 0; i < 4; ++i)
                #pragma unroll
                for (int j = 0; j < 4; ++j)
                    acc[i][j] = fmaf(av[i], bv[j], acc[i][j]);
        }
        __syncthreads();
    }
    #pragma unroll
    for (int i = 0; i < 4; ++i) {
        float4 o4 = make_float4(acc[i][0], acc[i][1], acc[i][2], acc[i][3]);
        *(float4*)&out[(size_t)(m0 + ty * 4 + i) * EMB + n0 + tx * 4] = o4;
    }
}

// ---------------- flash attention: causal, scale 1/16, bf16 output ----------------
#define QB 16
#define KB 16
__global__ __launch_bounds__(256) void k_attn(const float* __restrict__ q,
                                              const float* __restrict__ k,
                                              const float* __restrict__ v,
                                              ushort* __restrict__ o) {
    int b = blockIdx.y, qt = blockIdx.x;
    int tid = threadIdx.x;
    __shared__ float q_s[QB][260];
    __shared__ float k_s[KB][260];
    __shared__ float v_s[KB][EMB];
    __shared__ float p_s[QB][KB];
    __shared__ float mrow[QB], lrow[QB], arow[QB];

    const float* qb = q + (size_t)(b * TSEQ + qt * QB) * EMB;
    for (int i = tid; i < QB * EMB / 4; i += 256) {
        float4 t4 = ((const float4*)qb)[i];
        *(float4*)&q_s[i >> 6][(i & 63) * 4] = t4;
    }
    if (tid < QB) { mrow[tid] = -1e30f; lrow[tid] = 0.f; }
    float acc[QB];
    #pragma unroll
    for (int i = 0; i < QB; ++i) acc[i] = 0.f;
    int qi = tid >> 4, si = tid & 15;
    int e = tid;
    __syncthreads();

    for (int st = 0; st <= qt; ++st) {
        const float* kb = k + (size_t)(b * TSEQ + st * KB) * EMB;
        const float* vb = v + (size_t)(b * TSEQ + st * KB) * EMB;
        for (int i = tid; i < KB * EMB / 4; i += 256) {
            float4 k4 = ((const float4*)kb)[i];
            float4 v4 = ((const float4*)vb)[i];
            *(float4*)&k_s[i >> 6][(i & 63) * 4] = k4;
            *(float4*)&v_s[i >> 6][(i & 63) * 4] = v4;
        }
        __syncthreads();

        float s = 0.f;
        #pragma unroll 8
        for (int c = 0; c < EMB; c += 4) {
            float4 qv = *(const float4*)&q_s[qi][c];
            float4 kv = *(const float4*)&k_s[si][c];
            s = fmaf(qv.x, kv.x, s);
            s = fmaf(qv.y, kv.y, s);
            s = fmaf(qv.z, kv.z, s);
            s = fmaf(qv.w, kv.w, s);
        }
        s *= 0.0625f;
        if (st == qt && si > qi) s = -1e30f;

        float mt = s;
        #pragma unroll
        for (int off = 8; off; off >>= 1)
            mt = fmaxf(mt, __shfl_xor(mt, off, 16));
        float mo = mrow[qi];
        float mn = fmaxf(mo, mt);
        float p = __expf(s - mn);
        float lt = p;
        #pragma unroll
        for (int off = 8; off; off >>= 1)
            lt += __shfl_xor(lt, off, 16);
        p_s[qi][si] = p;
        if (si == 0) {
            float a = __expf(mo - mn);
            arow[qi] = a;
            mrow[qi] = mn;
            lrow[qi] = lrow[qi] * a + lt;
        }
        __syncthreads();

        #pragma unroll
        for (int r = 0; r < QB; ++r) {
            float a = arow[r];
            float sum = 0.f;
            #pragma unroll
            for (int ss = 0; ss < KB; ++ss)
                sum = fmaf(p_s[r][ss], v_s[ss][e], sum);
            acc[r] = acc[r] * a + sum;
        }
        __syncthreads();
    }

    ushort* ob = o + (size_t)(b * TSEQ + qt * QB) * EMB;
    #pragma unroll
    for (int r = 0; r < QB; ++r) {
        __hip_bfloat16 h = __float2bfloat16(acc[r] / lrow[r]);
        ob[r * EMB + e] = *(ushort*)&h;
    }
}

// ---------------- transpose + convert lm_W -> Wt[32000][256] bf16 ----------------
__global__ __launch_bounds__(256) void k_convW(const float* __restrict__ W,
                                               ushort* __restrict__ Wt) {
    __shared__ float T[32][33];
    int n0 = blockIdx.x * 32, k0 = blockIdx.y * 32;
    int tx = threadIdx.x & 31, ty = threadIdx.x >> 5;   // ty 0..7
    #pragma unroll
    for (int i = 0; i < 4; ++i) {
        int kk = ty + 8 * i;
        T[kk][tx] = W[(size_t)(k0 + kk) * VOCAB + n0 + tx];
    }
    __syncthreads();
    #pragma unroll
    for (int i = 0; i < 4; ++i) {
        int r = ty + 8 * i;                             // n offset
        __hip_bfloat16 h = __float2bfloat16(T[tx][r]);
        Wt[(size_t)(n0 + r) * EMB + k0 + tx] = *(ushort*)&h;
    }
}

// ---------------- logits GEMM: [4096,256] bf16 @ [256,32000] bf16 -> fp32 ----------------
// A = ao [4096][256] bf16, Bt = Wt [32000][256] bf16. 128x128 tile, BK=64,
// 4 waves (2x2), 64x64 per wave, mfma_f32_16x16x32_bf16.
// LDS linear [128][64] bf16, XOR-swizzled via pre-swizzled global source (m173):
// LDS[row][chunk p] holds global chunk p^(row&7); reads XOR the same way.
__global__ __launch_bounds__(256) void k_gemm(const ushort* __restrict__ A,
                                              const ushort* __restrict__ Bt,
                                              const float* __restrict__ lmb,
                                              float* __restrict__ C) {
    __shared__ ushort As[128 * 64];
    __shared__ ushort Bs[128 * 64];

    int tid = threadIdx.x;
    int lane = tid & 63, wave = tid >> 6;
    int wm = wave >> 1, wn = wave & 1;
    int m0 = blockIdx.x * 128, n0 = blockIdx.y * 128;

    int lr = lane >> 3;        // staging row-in-group 0..7
    int cc = lane & 7;         // staging chunk 0..7
    int lrow = lane & 15, lk = lane >> 4;   // mfma fragment indices

    f32x4 acc[4][4];
    #pragma unroll
    for (int i = 0; i < 4; ++i)
        #pragma unroll
        for (int j = 0; j < 4; ++j)
            acc[i][j] = (f32x4){0.f, 0.f, 0.f, 0.f};

    for (int k0 = 0; k0 < EMB; k0 += 64) {
        // stage A and B tiles: 4 calls each, 8 rows/wave/call
        #pragma unroll
        for (int j = 0; j < 4; ++j) {
            int rbase = j * 32 + wave * 8;
            int row = rbase + lr;
            int cs = cc ^ (row & 7);
            const ushort* ga = A + (size_t)(m0 + row) * EMB + k0 + cs * 8;
            const ushort* gb = Bt + (size_t)(n0 + row) * EMB + k0 + cs * 8;
            __builtin_amdgcn_global_load_lds(
                (const __attribute__((address_space(1))) void*)ga,
                (__attribute__((address_space(3))) void*)&As[rbase * 64], 16, 0, 0);
            __builtin_amdgcn_global_load_lds(
                (const __attribute__((address_space(1))) void*)gb,
                (__attribute__((address_space(3))) void*)&Bs[rbase * 64], 16, 0, 0);
        }
        __syncthreads();

        #pragma unroll
        for (int kk = 0; kk < 2; ++kk) {
            short8 a[4], b[4];
            #pragma unroll
            for (int m = 0; m < 4; ++m) {
                int row = wm * 64 + m * 16 + lrow;
                int c2 = (kk * 4 + lk) ^ (row & 7);
                a[m] = *(const short8*)&As[row * 64 + c2 * 8];
            }
            #pragma unroll
            for (int n = 0; n < 4; ++n) {
                int row = wn * 64 + n * 16 + lrow;
                int c2 = (kk * 4 + lk) ^ (row & 7);
                b[n] = *(const short8*)&Bs[row * 64 + c2 * 8];
            }
            #pragma unroll
            for (int m = 0; m < 4; ++m)
                #pragma unroll
                for (int n = 0; n < 4; ++n)
                    acc[m][n] = __builtin_amdgcn_mfma_f32_16x16x32_bf16(
                        a[m], b[n], acc[m][n], 0, 0, 0);
        }
        __syncthreads();
    }

    // epilogue: C[row][col] = acc + lmb[col]
    #pragma unroll
    for (int n = 0; n < 4; ++n) {
        int col = n0 + wn * 64 + n * 16 + lrow;
        float bias = lmb[col];
        #pragma unroll
        for (int m = 0; m < 4; ++m) {
            int rbase = m0 + wm * 64 + m * 16 + lk * 4;
            #pragma unroll
            for (int j = 0; j < 4; ++j)
                C[(size_t)(rbase + j) * VOCAB + col] = acc[m][n][j] + bias;
        }
    }
}

// ---------------- loss: per-row logsumexp over logits ----------------
__global__ __launch_bounds__(256) void k_loss(const float* __restrict__ logits,
                                              const int* __restrict__ tgt,
                                              float* __restrict__ loss) {
    int row = blockIdx.x;
    const float* lr = logits + (size_t)row * VOCAB;
    int tid = threadIdx.x;
    float m = -1e30f, s = 0.f;
    for (int c = tid; c < VOCAB; c += 256) {
        float val = lr[c];
        float mn = fmaxf(m, val);
        s = s * __expf(m - mn) + __expf(val - mn);
        m = mn;
    }
    #pragma unroll
    for (int off = 1; off < 64; off <<= 1) {
        float mo = __shfl_xor(m, off, 64);
        float so = __shfl_xor(s, off, 64);
        float mn = fmaxf(m, mo);
        s = s * __expf(m - mn) + so * __expf(mo - mn);
        m = mn;
    }
    __shared__ float wm[4], wsum[4];
    int lane = tid & 63, wave = tid >> 6;
    if (lane == 0) { wm[wave] = m; wsum[wave] = s; }
    __syncthreads();
    if (tid == 0) {
        float M = wm[0], S = wsum[0];
        #pragma unroll
        for (int w = 1; w < 4; ++w) {
            float mn = fmaxf(M, wm[w]);
            S = S * __expf(M - mn) + wsum[w] * __expf(wm[w] - mn);
            M = mn;
        }
        float lse = M + __logf(S);
        float tl = lr[tgt[row]];
        atomicAdd(loss, (lse - tl) * (1.0f / 4096.0f));
    }
}

extern "C" void kernel_launch(void* const* d_in, const int* in_sizes, int n_in,
                              void* d_out, int out_size, void* d_ws, size_t ws_size,
                              hipStream_t stream) {
    (void)in_sizes; (void)n_in; (void)ws_size;
    const int*   idx     = (const int*)d_in[0];
    const int*   targets = (const int*)d_in[1];
    const float* tok     = (const float*)d_in[2];
    const float* pos     = (const float*)d_in[3];
    const float* Wk      = (const float*)d_in[4];
    const float* Wq      = (const float*)d_in[5];
    const float* Wv      = (const float*)d_in[6];
    const float* lmW     = (const float*)d_in[7];
    const float* lmb     = (const float*)d_in[8];

    float* logits = (float*)d_out;
    float* loss   = logits + (size_t)out_size - 1;

    float* ws = (float*)d_ws;
    float* x  = ws;
    float* q  = ws + (1u << 20);
    float* k  = ws + 2u * (1u << 20);
    float* v  = ws + 3u * (1u << 20);
    ushort* ao = (ushort*)(ws + 4u * (1u << 20));          // 2 MB bf16
    ushort* Wt = ao + (size_t)NROWS * EMB;                 // 16 MB bf16

    k_convW<<<dim3(VOCAB / 32, EMB / 32), 256, 0, stream>>>(lmW, Wt);
    k_embed<<<NROWS, 256, 0, stream>>>(idx, tok, pos, x);
    k_qkv<<<dim3(NROWS / 64, EMB / 64, 3), 256, 0, stream>>>(x, Wq, Wk, Wv, q, k, v);
    k_attn<<<dim3(TSEQ / QB, 4), 256, 0, stream>>>(q, k, v, ao);
    k_gemm<<<dim3(NROWS / 128, VOCAB / 128), 256, 0, stream>>>(ao, Wt, lmb, logits);
    hipMemsetAsync(loss, 0, sizeof(float), stream);
    k_loss<<<NROWS, 256, 0, stream>>>(logits, targets, loss);
}

// Round 3
// 377.953 us; speedup vs baseline: 7.6624x; 1.7833x over previous
//
#include <hip/hip_runtime.h>
#include <hip/hip_bf16.h>
#include <math.h>

#define VOCAB 32000
#define EMB   256
#define TSEQ  1024
#define NROWS 4096
#define NBLKN 250   // VOCAB/128

typedef __attribute__((ext_vector_type(8))) short short8;
typedef __attribute__((ext_vector_type(4))) float f32x4;

static __device__ __forceinline__ unsigned short bfb(float x) {
    __hip_bfloat16 h = __float2bfloat16(x);
    return *(unsigned short*)&h;
}
static __device__ __forceinline__ unsigned pk2(float a, float b) {
    return (unsigned)bfb(a) | ((unsigned)bfb(b) << 16);
}

// ---------------- embed: x = tok_table[idx] + pos_table[t] ----------------
__global__ __launch_bounds__(256) void k_embed(const int* __restrict__ idx,
                                               const float* __restrict__ tok,
                                               const float* __restrict__ pos,
                                               float* __restrict__ x) {
    int row = blockIdx.x;
    int t = row & (TSEQ - 1);
    int token = idx[row];
    int e = threadIdx.x;
    x[row * EMB + e] = tok[token * EMB + e] + pos[t * EMB + e];
}

// ---------------- qkv: [4096,256] @ [256,256] -> bf16 q/k, transposed bf16 Vt ----------------
__global__ __launch_bounds__(256) void k_qkv(const float* __restrict__ x,
                                             const float* __restrict__ Wq,
                                             const float* __restrict__ Wk,
                                             const float* __restrict__ Wv,
                                             ushort* __restrict__ qb,
                                             ushort* __restrict__ kbf,
                                             ushort* __restrict__ vt) {
    const float* W;
    if (blockIdx.z == 0)      W = Wq;
    else if (blockIdx.z == 1) W = Wk;
    else                      W = Wv;

    __shared__ float As[16][68];
    __shared__ float Bs[16][64];

    int tid = threadIdx.x;
    int tx = tid & 15, ty = tid >> 4;
    int m0 = blockIdx.x * 64, n0 = blockIdx.y * 64;

    float acc[4][4] = {};
    for (int k0 = 0; k0 < EMB; k0 += 16) {
        #pragma unroll
        for (int i = 0; i < 4; ++i) {
            int lin = tid + i * 256;
            int mm = lin >> 4, kk = lin & 15;
            As[kk][mm] = x[(m0 + mm) * EMB + k0 + kk];
        }
        #pragma unroll
        for (int i = 0; i < 4; ++i) {
            int lin = tid + i * 256;
            int kk = lin >> 6, nn = lin & 63;
            Bs[kk][nn] = W[(k0 + kk) * EMB + n0 + nn];
        }
        __syncthreads();
        #pragma unroll
        for (int kk = 0; kk < 16; ++kk) {
            float4 a4 = *(const float4*)&As[kk][ty * 4];
            float4 b4 = *(const float4*)&Bs[kk][tx * 4];
            float av[4] = {a4.x, a4.y, a4.z, a4.w};
            float bv[4] = {b4.x, b4.y, b4.z, b4.w};
            #pragma unroll
            for (int i = 0; i < 4; ++i)
                #pragma unroll
                for (int j = 0; j < 4; ++j)
                    acc[i][j] = fmaf(av[i], bv[j], acc[i][j]);
        }
        __syncthreads();
    }
    if (blockIdx.z < 2) {
        ushort* out = (blockIdx.z == 0) ? qb : kbf;
        #pragma unroll
        for (int i = 0; i < 4; ++i) {
            uint2 w;
            w.x = pk2(acc[i][0], acc[i][1]);
            w.y = pk2(acc[i][2], acc[i][3]);
            *(uint2*)&out[(size_t)(m0 + ty * 4 + i) * EMB + n0 + tx * 4] = w;
        }
    } else {
        // Vt[b][e][row_in_batch]
        #pragma unroll
        for (int i = 0; i < 4; ++i) {
            int row = m0 + ty * 4 + i;
            int bb = row >> 10, rr = row & 1023;
            #pragma unroll
            for (int j = 0; j < 4; ++j)
                vt[((size_t)bb * EMB + (n0 + tx * 4 + j)) * TSEQ + rr] = bfb(acc[i][j]);
        }
    }
}

// ---------------- MFMA flash attention: 1 wave per 16 Q-rows, KB=32 ----------------
// S^T = mfma(K, Q); softmax per q via shfl_xor(16,32); P shuffled to B-frag; O^T = mfma(Vt, P).
__global__ __launch_bounds__(64) void k_attn(const ushort* __restrict__ qg,
                                             const ushort* __restrict__ kg,
                                             const ushort* __restrict__ vt,
                                             ushort* __restrict__ ao) {
    __shared__ ushort K_s[32 * 256];   // [key][256], chunk-XOR-swizzled (^(key&7))
    __shared__ ushort V_s[256 * 32];   // [e][32 keys], slot-XOR-swizzled (^(e&3))

    int strip = blockIdx.x;            // 0..255
    int b = strip >> 6;
    int qbase = (strip & 63) * 16;
    int lane = threadIdx.x;
    int q = lane & 15, lk = lane >> 4;

    // Q fragments (B-operand layout): row=q, k = c*32 + lk*8 + j
    const ushort* qrow = qg + (size_t)(b * TSEQ + qbase + q) * EMB;
    short8 qf[8];
    #pragma unroll
    for (int c = 0; c < 8; ++c)
        qf[c] = *(const short8*)&qrow[c * 32 + lk * 8];

    f32x4 o[16];
    #pragma unroll
    for (int i = 0; i < 16; ++i) o[i] = (f32x4){0.f, 0.f, 0.f, 0.f};
    float m_run = -1e30f, l_run = 0.f;

    int st_last = (qbase + 15) >> 5;
    for (int st = 0; st <= st_last; ++st) {
        // stage K tile [32][256] bf16: 16 calls, 2 rows/call
        const ushort* kbase = kg + (size_t)(b * TSEQ + st * 32) * EMB;
        #pragma unroll
        for (int t = 0; t < 16; ++t) {
            int r = t * 2 + (lane >> 5);
            int slot = lane & 31;
            int chunk = slot ^ (r & 7);
            const ushort* src = kbase + r * EMB + chunk * 8;
            __builtin_amdgcn_global_load_lds(
                (const __attribute__((address_space(1))) void*)src,
                (__attribute__((address_space(3))) void*)&K_s[t * 512], 16, 0, 0);
        }
        // stage Vt tile [256][32] bf16: 16 calls, 16 rows/call
        #pragma unroll
        for (int t = 0; t < 16; ++t) {
            int e = t * 16 + (lane >> 2);
            int slot = lane & 3;
            int chunk = slot ^ (e & 3);
            const ushort* src = vt + ((size_t)b * EMB + e) * TSEQ + st * 32 + chunk * 8;
            __builtin_amdgcn_global_load_lds(
                (const __attribute__((address_space(1))) void*)src,
                (__attribute__((address_space(3))) void*)&V_s[t * 512], 16, 0, 0);
        }
        asm volatile("s_waitcnt vmcnt(0)" ::: "memory");

        // QK^T: S^T[key][q], key groups g=0 (0-15), g=1 (16-31)
        f32x4 sa0 = (f32x4){0.f, 0.f, 0.f, 0.f};
        f32x4 sa1 = (f32x4){0.f, 0.f, 0.f, 0.f};
        #pragma unroll
        for (int c = 0; c < 8; ++c) {
            int sl = (c * 4 + lk) ^ (q & 7);
            short8 kf0 = *(const short8*)&K_s[q * 256 + sl * 8];
            short8 kf1 = *(const short8*)&K_s[(16 + q) * 256 + sl * 8];
            sa0 = __builtin_amdgcn_mfma_f32_16x16x32_bf16(kf0, qf[c], sa0, 0, 0, 0);
            sa1 = __builtin_amdgcn_mfma_f32_16x16x32_bf16(kf1, qf[c], sa1, 0, 0, 0);
        }

        float sv0[4], sv1[4];
        #pragma unroll
        for (int j = 0; j < 4; ++j) { sv0[j] = sa0[j] * 0.0625f; sv1[j] = sa1[j] * 0.0625f; }
        if (st == st_last) {
            int qgl = qbase + q;
            #pragma unroll
            for (int j = 0; j < 4; ++j) {
                if (st * 32 + lk * 4 + j > qgl)      sv0[j] = -1e30f;
                if (st * 32 + 16 + lk * 4 + j > qgl) sv1[j] = -1e30f;
            }
        }

        // online softmax per q (reduce over lk groups: lanes q, q+16, q+32, q+48)
        float tm = sv0[0];
        #pragma unroll
        for (int j = 1; j < 4; ++j) tm = fmaxf(tm, sv0[j]);
        #pragma unroll
        for (int j = 0; j < 4; ++j) tm = fmaxf(tm, sv1[j]);
        tm = fmaxf(tm, __shfl_xor(tm, 16));
        tm = fmaxf(tm, __shfl_xor(tm, 32));
        float mn = fmaxf(m_run, tm);
        float alpha = __expf(m_run - mn);
        float p0[4], p1[4], ts = 0.f;
        #pragma unroll
        for (int j = 0; j < 4; ++j) {
            p0[j] = __expf(sv0[j] - mn);
            p1[j] = __expf(sv1[j] - mn);
            ts += p0[j] + p1[j];
        }
        ts += __shfl_xor(ts, 16);
        ts += __shfl_xor(ts, 32);
        l_run = l_run * alpha + ts;
        m_run = mn;

        // rescale O
        #pragma unroll
        for (int i = 0; i < 16; ++i) {
            o[i][0] *= alpha; o[i][1] *= alpha; o[i][2] *= alpha; o[i][3] *= alpha;
        }

        // redistribute P (C-layout) -> B-frag (keys lk*8..lk*8+7, col=q)
        unsigned c0 = pk2(p0[0], p0[1]), c1 = pk2(p0[2], p0[3]);
        unsigned d0 = pk2(p1[0], p1[1]), d1 = pk2(p1[2], p1[3]);
        int sA = q + 32 * (lk & 1);
        int sB = sA + 16;
        unsigned a0c = __shfl(c0, sA), a1c = __shfl(c1, sA);
        unsigned b0c = __shfl(c0, sB), b1c = __shfl(c1, sB);
        unsigned a0d = __shfl(d0, sA), a1d = __shfl(d1, sA);
        unsigned b0d = __shfl(d0, sB), b1d = __shfl(d1, sB);
        bool hi = (lk >> 1) != 0;
        union { short8 s; unsigned u[4]; } pb;
        pb.u[0] = hi ? a0d : a0c;
        pb.u[1] = hi ? a1d : a1c;
        pb.u[2] = hi ? b0d : b0c;
        pb.u[3] = hi ? b1d : b1c;

        // PV: O^T[e][q] += Vt-frag * P
        #pragma unroll
        for (int eb = 0; eb < 16; ++eb) {
            int er = eb * 16 + q;
            int sl = lk ^ (er & 3);
            short8 vf = *(const short8*)&V_s[er * 32 + sl * 8];
            o[eb] = __builtin_amdgcn_mfma_f32_16x16x32_bf16(vf, pb.s, o[eb], 0, 0, 0);
        }
    }

    float inv_l = 1.f / l_run;
    ushort* orow = ao + (size_t)(b * TSEQ + qbase + q) * EMB;
    #pragma unroll
    for (int eb = 0; eb < 16; ++eb) {
        uint2 w;
        w.x = pk2(o[eb][0] * inv_l, o[eb][1] * inv_l);
        w.y = pk2(o[eb][2] * inv_l, o[eb][3] * inv_l);
        *(uint2*)&orow[eb * 16 + lk * 4] = w;
    }
}

// ---------------- transpose + convert lm_W -> Wt[32000][256] bf16 ----------------
__global__ __launch_bounds__(256) void k_convW(const float* __restrict__ W,
                                               ushort* __restrict__ Wt) {
    __shared__ float T[32][33];
    int n0 = blockIdx.x * 32, k0 = blockIdx.y * 32;
    int tx = threadIdx.x & 31, ty = threadIdx.x >> 5;
    #pragma unroll
    for (int i = 0; i < 4; ++i) {
        int kk = ty + 8 * i;
        T[kk][tx] = W[(size_t)(k0 + kk) * VOCAB + n0 + tx];
    }
    __syncthreads();
    #pragma unroll
    for (int i = 0; i < 4; ++i) {
        int r = ty + 8 * i;
        Wt[(size_t)(n0 + r) * EMB + k0 + tx] = bfb(T[tx][r]);
    }
}

// ---------------- logits GEMM + fused per-block logsumexp partials ----------------
__global__ __launch_bounds__(256) void k_gemm(const ushort* __restrict__ A,
                                              const ushort* __restrict__ Bt,
                                              const float* __restrict__ lmb,
                                              float* __restrict__ C,
                                              float2* __restrict__ part) {
    __shared__ ushort As[128 * 64];
    __shared__ ushort Bs[128 * 64];

    int linear = blockIdx.x;
    int swz = (linear & 7) * 1000 + (linear >> 3);   // bijective XCD swizzle (8000%8==0)
    int m0 = (swz & 31) * 128;
    int nb = swz >> 5;
    int n0 = nb * 128;

    int tid = threadIdx.x;
    int lane = tid & 63, wave = tid >> 6;
    int wm = wave >> 1, wn = wave & 1;

    int lr = lane >> 3;
    int cc = lane & 7;
    int lrow = lane & 15, lk = lane >> 4;

    f32x4 acc[4][4];
    #pragma unroll
    for (int i = 0; i < 4; ++i)
        #pragma unroll
        for (int j = 0; j < 4; ++j)
            acc[i][j] = (f32x4){0.f, 0.f, 0.f, 0.f};

    for (int k0 = 0; k0 < EMB; k0 += 64) {
        #pragma unroll
        for (int j = 0; j < 4; ++j) {
            int rbase = j * 32 + wave * 8;
            int row = rbase + lr;
            int cs = cc ^ (row & 7);
            const ushort* ga = A + (size_t)(m0 + row) * EMB + k0 + cs * 8;
            const ushort* gb = Bt + (size_t)(n0 + row) * EMB + k0 + cs * 8;
            __builtin_amdgcn_global_load_lds(
                (const __attribute__((address_space(1))) void*)ga,
                (__attribute__((address_space(3))) void*)&As[rbase * 64], 16, 0, 0);
            __builtin_amdgcn_global_load_lds(
                (const __attribute__((address_space(1))) void*)gb,
                (__attribute__((address_space(3))) void*)&Bs[rbase * 64], 16, 0, 0);
        }
        __syncthreads();

        #pragma unroll
        for (int kk = 0; kk < 2; ++kk) {
            short8 a[4], b[4];
            #pragma unroll
            for (int m = 0; m < 4; ++m) {
                int row = wm * 64 + m * 16 + lrow;
                int c2 = (kk * 4 + lk) ^ (row & 7);
                a[m] = *(const short8*)&As[row * 64 + c2 * 8];
            }
            #pragma unroll
            for (int n = 0; n < 4; ++n) {
                int row = wn * 64 + n * 16 + lrow;
                int c2 = (kk * 4 + lk) ^ (row & 7);
                b[n] = *(const short8*)&Bs[row * 64 + c2 * 8];
            }
            #pragma unroll
            for (int m = 0; m < 4; ++m)
                #pragma unroll
                for (int n = 0; n < 4; ++n)
                    acc[m][n] = __builtin_amdgcn_mfma_f32_16x16x32_bf16(
                        a[m], b[n], acc[m][n], 0, 0, 0);
        }
        __syncthreads();
    }

    float biasv[4];
    #pragma unroll
    for (int n = 0; n < 4; ++n)
        biasv[n] = lmb[n0 + wn * 64 + n * 16 + lrow];

    // write logits
    #pragma unroll
    for (int n = 0; n < 4; ++n) {
        int col = n0 + wn * 64 + n * 16 + lrow;
        #pragma unroll
        for (int m = 0; m < 4; ++m) {
            int rbase = m0 + wm * 64 + m * 16 + lk * 4;
            #pragma unroll
            for (int j = 0; j < 4; ++j)
                C[(size_t)(rbase + j) * VOCAB + col] = acc[m][n][j] + biasv[n];
        }
    }

    // per-row logsumexp partial over this block's 128 cols
    float pM[4][4], pS[4][4];
    #pragma unroll
    for (int m = 0; m < 4; ++m) {
        #pragma unroll
        for (int j = 0; j < 4; ++j) {
            float v0 = acc[m][0][j] + biasv[0];
            float v1 = acc[m][1][j] + biasv[1];
            float v2 = acc[m][2][j] + biasv[2];
            float v3 = acc[m][3][j] + biasv[3];
            float tM = fmaxf(fmaxf(v0, v1), fmaxf(v2, v3));
            float tS = __expf(v0 - tM) + __expf(v1 - tM) + __expf(v2 - tM) + __expf(v3 - tM);
            #pragma unroll
            for (int off = 1; off < 16; off <<= 1) {
                float oM = __shfl_xor(tM, off);
                float oS = __shfl_xor(tS, off);
                float nM = fmaxf(tM, oM);
                tS = tS * __expf(tM - nM) + oS * __expf(oM - nM);
                tM = nM;
            }
            pM[m][j] = tM; pS[m][j] = tS;
        }
    }
    float* fb = (float*)As;   // reuse LDS (all waves past last barrier reads)
    __syncthreads();
    if (wn == 0 && lrow == 0) {
        #pragma unroll
        for (int m = 0; m < 4; ++m)
            #pragma unroll
            for (int j = 0; j < 4; ++j) {
                int r64 = m * 16 + lk * 4 + j;
                fb[wm * 64 + r64] = pM[m][j];
                fb[128 + wm * 64 + r64] = pS[m][j];
            }
    }
    __syncthreads();
    if (wn == 1 && lrow == 0) {
        #pragma unroll
        for (int m = 0; m < 4; ++m)
            #pragma unroll
            for (int j = 0; j < 4; ++j) {
                int r64 = m * 16 + lk * 4 + j;
                float oM = fb[wm * 64 + r64];
                float oS = fb[128 + wm * 64 + r64];
                float tM = pM[m][j], tS = pS[m][j];
                float nM = fmaxf(tM, oM);
                float nS = tS * __expf(tM - nM) + oS * __expf(oM - nM);
                part[(size_t)(m0 + wm * 64 + r64) * NBLKN + nb] = make_float2(nM, nS);
            }
    }
}

// ---------------- loss reduce over partials ----------------
__global__ __launch_bounds__(256) void k_reduce(const float2* __restrict__ part,
                                                const float* __restrict__ logits,
                                                const int* __restrict__ tgt,
                                                float* __restrict__ loss) {
    int row = blockIdx.x;
    int tid = threadIdx.x;
    float M = -1e30f, S = 0.f;
    for (int i = tid; i < NBLKN; i += 256) {
        float2 p = part[(size_t)row * NBLKN + i];
        float nM = fmaxf(M, p.x);
        S = S * __expf(M - nM) + p.y * __expf(p.x - nM);
        M = nM;
    }
    #pragma unroll
    for (int off = 1; off < 64; off <<= 1) {
        float oM = __shfl_xor(M, off);
        float oS = __shfl_xor(S, off);
        float nM = fmaxf(M, oM);
        S = S * __expf(M - nM) + oS * __expf(oM - nM);
        M = nM;
    }
    __shared__ float wm[4], ws[4];
    int lane = tid & 63, wave = tid >> 6;
    if (lane == 0) { wm[wave] = M; ws[wave] = S; }
    __syncthreads();
    if (tid == 0) {
        float fM = wm[0], fS = ws[0];
        #pragma unroll
        for (int w = 1; w < 4; ++w) {
            float nM = fmaxf(fM, wm[w]);
            fS = fS * __expf(fM - nM) + ws[w] * __expf(wm[w] - nM);
            fM = nM;
        }
        float lse = fM + __logf(fS);
        float tl = logits[(size_t)row * VOCAB + tgt[row]];
        atomicAdd(loss, (lse - tl) * (1.0f / 4096.0f));
    }
}

extern "C" void kernel_launch(void* const* d_in, const int* in_sizes, int n_in,
                              void* d_out, int out_size, void* d_ws, size_t ws_size,
                              hipStream_t stream) {
    (void)in_sizes; (void)n_in; (void)ws_size;
    const int*   idx     = (const int*)d_in[0];
    const int*   targets = (const int*)d_in[1];
    const float* tok     = (const float*)d_in[2];
    const float* pos     = (const float*)d_in[3];
    const float* Wk      = (const float*)d_in[4];
    const float* Wq      = (const float*)d_in[5];
    const float* Wv      = (const float*)d_in[6];
    const float* lmW     = (const float*)d_in[7];
    const float* lmb     = (const float*)d_in[8];

    float* logits = (float*)d_out;
    float* loss   = logits + (size_t)out_size - 1;

    char* w = (char*)d_ws;
    float*  x    = (float*)w;                          // 4 MB
    ushort* Wt   = (ushort*)(w + (4u << 20));          // 16 MB
    ushort* qb   = (ushort*)(w + (20u << 20));         // 2 MB
    ushort* kbf  = (ushort*)(w + (22u << 20));         // 2 MB
    ushort* vt   = (ushort*)(w + (24u << 20));         // 2 MB
    ushort* ao   = (ushort*)(w + (26u << 20));         // 2 MB
    float2* part = (float2*)(w + (28u << 20));         // 8.2 MB

    k_convW<<<dim3(VOCAB / 32, EMB / 32), 256, 0, stream>>>(lmW, Wt);
    k_embed<<<NROWS, 256, 0, stream>>>(idx, tok, pos, x);
    k_qkv<<<dim3(NROWS / 64, EMB / 64, 3), 256, 0, stream>>>(x, Wq, Wk, Wv, qb, kbf, vt);
    k_attn<<<256, 64, 0, stream>>>(qb, kbf, vt, ao);
    k_gemm<<<8000, 256, 0, stream>>>(ao, Wt, lmb, logits, part);
    hipMemsetAsync(loss, 0, sizeof(float), stream);
    k_reduce<<<NROWS, 256, 0, stream>>>(part, logits, targets, loss);
}

// Round 4
// 338.988 us; speedup vs baseline: 8.5432x; 1.1149x over previous
//
#include <hip/hip_runtime.h>
#include <hip/hip_bf16.h>
#include <math.h>

#define VOCAB 32000
#define EMB   256
#define TSEQ  1024
#define NROWS 4096
#define NBLKN 250   // VOCAB/128

typedef __attribute__((ext_vector_type(8))) short short8;
typedef __attribute__((ext_vector_type(4))) float f32x4;

static __device__ __forceinline__ unsigned short bfb(float x) {
    __hip_bfloat16 h = __float2bfloat16(x);
    return *(unsigned short*)&h;
}
static __device__ __forceinline__ unsigned pk2(float a, float b) {
    return (unsigned)bfb(a) | ((unsigned)bfb(b) << 16);
}

// ---------------- embed: xb = bf16(tok_table[idx] + pos_table[t]) ----------------
__global__ __launch_bounds__(256) void k_embed(const int* __restrict__ idx,
                                               const float* __restrict__ tok,
                                               const float* __restrict__ pos,
                                               ushort* __restrict__ xb) {
    int row = blockIdx.x;
    int t = row & (TSEQ - 1);
    int token = idx[row];
    int e = threadIdx.x;
    xb[row * EMB + e] = bfb(tok[token * EMB + e] + pos[t * EMB + e]);
}

// ---------------- transpose + convert lm_W -> Wt[32000][256] bf16 ----------------
__global__ __launch_bounds__(256) void k_convW(const float* __restrict__ W,
                                               ushort* __restrict__ Wt) {
    __shared__ float T[32][33];
    int n0 = blockIdx.x * 32, k0 = blockIdx.y * 32;
    int tx = threadIdx.x & 31, ty = threadIdx.x >> 5;
    #pragma unroll
    for (int i = 0; i < 4; ++i) {
        int kk = ty + 8 * i;
        T[kk][tx] = W[(size_t)(k0 + kk) * VOCAB + n0 + tx];
    }
    __syncthreads();
    #pragma unroll
    for (int i = 0; i < 4; ++i) {
        int r = ty + 8 * i;
        Wt[(size_t)(n0 + r) * EMB + k0 + tx] = bfb(T[tx][r]);
    }
}

// ---------------- transpose + convert Wq/Wk/Wv [256][256] fp32 -> [n][k] bf16 ----------------
__global__ __launch_bounds__(256) void k_convw3(const float* __restrict__ Wq,
                                                const float* __restrict__ Wk,
                                                const float* __restrict__ Wv,
                                                ushort* __restrict__ Wt3) {
    const float* W = (blockIdx.z == 0) ? Wq : (blockIdx.z == 1) ? Wk : Wv;
    ushort* out = Wt3 + (size_t)blockIdx.z * EMB * EMB;
    __shared__ float T[32][33];
    int n0 = blockIdx.x * 32, k0 = blockIdx.y * 32;
    int tx = threadIdx.x & 31, ty = threadIdx.x >> 5;
    #pragma unroll
    for (int i = 0; i < 4; ++i) {
        int kk = ty + 8 * i;
        T[kk][tx] = W[(size_t)(k0 + kk) * EMB + n0 + tx];
    }
    __syncthreads();
    #pragma unroll
    for (int i = 0; i < 4; ++i) {
        int r = ty + 8 * i;
        out[(size_t)(n0 + r) * EMB + k0 + tx] = bfb(T[tx][r]);
    }
}

// ---------------- qkv MFMA GEMM: xb[4096,256] @ Wt3[z] -> q/k/v bf16 row-major ----------------
__global__ __launch_bounds__(256) void k_qkv_mm(const ushort* __restrict__ A,
                                                const ushort* __restrict__ Wt3,
                                                ushort* __restrict__ qb,
                                                ushort* __restrict__ kbf,
                                                ushort* __restrict__ vb) {
    __shared__ ushort As[128 * 64];
    __shared__ ushort Bs[128 * 64];

    int z = blockIdx.z;
    const ushort* Bt = Wt3 + (size_t)z * EMB * EMB;
    ushort* out = (z == 0) ? qb : (z == 1) ? kbf : vb;

    int m0 = blockIdx.x * 128, n0 = blockIdx.y * 128;
    int tid = threadIdx.x;
    int lane = tid & 63, wave = tid >> 6;
    int wm = wave >> 1, wn = wave & 1;
    int lr = lane >> 3, cc = lane & 7;
    int lrow = lane & 15, lk = lane >> 4;

    f32x4 acc[4][4];
    #pragma unroll
    for (int i = 0; i < 4; ++i)
        #pragma unroll
        for (int j = 0; j < 4; ++j)
            acc[i][j] = (f32x4){0.f, 0.f, 0.f, 0.f};

    for (int k0 = 0; k0 < EMB; k0 += 64) {
        #pragma unroll
        for (int j = 0; j < 4; ++j) {
            int rbase = j * 32 + wave * 8;
            int row = rbase + lr;
            int cs = cc ^ (row & 7);
            const ushort* ga = A + (size_t)(m0 + row) * EMB + k0 + cs * 8;
            const ushort* gb = Bt + (size_t)(n0 + row) * EMB + k0 + cs * 8;
            __builtin_amdgcn_global_load_lds(
                (const __attribute__((address_space(1))) void*)ga,
                (__attribute__((address_space(3))) void*)&As[rbase * 64], 16, 0, 0);
            __builtin_amdgcn_global_load_lds(
                (const __attribute__((address_space(1))) void*)gb,
                (__attribute__((address_space(3))) void*)&Bs[rbase * 64], 16, 0, 0);
        }
        __syncthreads();
        #pragma unroll
        for (int kk = 0; kk < 2; ++kk) {
            short8 a[4], b[4];
            #pragma unroll
            for (int m = 0; m < 4; ++m) {
                int row = wm * 64 + m * 16 + lrow;
                int c2 = (kk * 4 + lk) ^ (row & 7);
                a[m] = *(const short8*)&As[row * 64 + c2 * 8];
            }
            #pragma unroll
            for (int n = 0; n < 4; ++n) {
                int row = wn * 64 + n * 16 + lrow;
                int c2 = (kk * 4 + lk) ^ (row & 7);
                b[n] = *(const short8*)&Bs[row * 64 + c2 * 8];
            }
            #pragma unroll
            for (int m = 0; m < 4; ++m)
                #pragma unroll
                for (int n = 0; n < 4; ++n)
                    acc[m][n] = __builtin_amdgcn_mfma_f32_16x16x32_bf16(
                        a[m], b[n], acc[m][n], 0, 0, 0);
        }
        __syncthreads();
    }

    #pragma unroll
    for (int n = 0; n < 4; ++n) {
        int col = n0 + wn * 64 + n * 16 + lrow;
        #pragma unroll
        for (int m = 0; m < 4; ++m) {
            int rbase = m0 + wm * 64 + m * 16 + lk * 4;
            #pragma unroll
            for (int j = 0; j < 4; ++j)
                out[(size_t)(rbase + j) * EMB + col] = bfb(acc[m][n][j]);
        }
    }
}

// ---------------- transpose v[4096][256] -> vt[4][256][1024] ----------------
__global__ __launch_bounds__(256) void k_vt(const ushort* __restrict__ vb,
                                            ushort* __restrict__ vt) {
    __shared__ ushort T[32][34];
    int t0 = blockIdx.x * 32;   // global row (b*1024 + t)
    int e0 = blockIdx.y * 32;
    int tx = threadIdx.x & 31, ty = threadIdx.x >> 5;
    #pragma unroll
    for (int i = 0; i < 4; ++i) {
        int r = ty + 8 * i;
        T[r][tx] = vb[(size_t)(t0 + r) * EMB + e0 + tx];
    }
    __syncthreads();
    int b = t0 >> 10, tl = t0 & 1023;
    #pragma unroll
    for (int i = 0; i < 4; ++i) {
        int r = ty + 8 * i;
        vt[((size_t)b * EMB + e0 + r) * TSEQ + tl + tx] = T[tx][r];
    }
}

// ---------------- MFMA flash attention: 1 wave per 16 Q-rows, KB=32 ----------------
__global__ __launch_bounds__(64) void k_attn(const ushort* __restrict__ qg,
                                             const ushort* __restrict__ kg,
                                             const ushort* __restrict__ vt,
                                             ushort* __restrict__ ao) {
    __shared__ ushort K_s[32 * 256];
    __shared__ ushort V_s[256 * 32];

    int strip = blockIdx.x;
    int b = strip >> 6;
    int qbase = (strip & 63) * 16;
    int lane = threadIdx.x;
    int q = lane & 15, lk = lane >> 4;

    const ushort* qrow = qg + (size_t)(b * TSEQ + qbase + q) * EMB;
    short8 qf[8];
    #pragma unroll
    for (int c = 0; c < 8; ++c)
        qf[c] = *(const short8*)&qrow[c * 32 + lk * 8];

    f32x4 o[16];
    #pragma unroll
    for (int i = 0; i < 16; ++i) o[i] = (f32x4){0.f, 0.f, 0.f, 0.f};
    float m_run = -1e30f, l_run = 0.f;

    int st_last = (qbase + 15) >> 5;
    for (int st = 0; st <= st_last; ++st) {
        const ushort* kbase = kg + (size_t)(b * TSEQ + st * 32) * EMB;
        #pragma unroll
        for (int t = 0; t < 16; ++t) {
            int r = t * 2 + (lane >> 5);
            int slot = lane & 31;
            int chunk = slot ^ (r & 7);
            const ushort* src = kbase + r * EMB + chunk * 8;
            __builtin_amdgcn_global_load_lds(
                (const __attribute__((address_space(1))) void*)src,
                (__attribute__((address_space(3))) void*)&K_s[t * 512], 16, 0, 0);
        }
        #pragma unroll
        for (int t = 0; t < 16; ++t) {
            int e = t * 16 + (lane >> 2);
            int slot = lane & 3;
            int chunk = slot ^ (e & 3);
            const ushort* src = vt + ((size_t)b * EMB + e) * TSEQ + st * 32 + chunk * 8;
            __builtin_amdgcn_global_load_lds(
                (const __attribute__((address_space(1))) void*)src,
                (__attribute__((address_space(3))) void*)&V_s[t * 512], 16, 0, 0);
        }
        asm volatile("s_waitcnt vmcnt(0)" ::: "memory");

        f32x4 sa0 = (f32x4){0.f, 0.f, 0.f, 0.f};
        f32x4 sa1 = (f32x4){0.f, 0.f, 0.f, 0.f};
        #pragma unroll
        for (int c = 0; c < 8; ++c) {
            int sl = (c * 4 + lk) ^ (q & 7);
            short8 kf0 = *(const short8*)&K_s[q * 256 + sl * 8];
            short8 kf1 = *(const short8*)&K_s[(16 + q) * 256 + sl * 8];
            sa0 = __builtin_amdgcn_mfma_f32_16x16x32_bf16(kf0, qf[c], sa0, 0, 0, 0);
            sa1 = __builtin_amdgcn_mfma_f32_16x16x32_bf16(kf1, qf[c], sa1, 0, 0, 0);
        }

        float sv0[4], sv1[4];
        #pragma unroll
        for (int j = 0; j < 4; ++j) { sv0[j] = sa0[j] * 0.0625f; sv1[j] = sa1[j] * 0.0625f; }
        if (st == st_last) {
            int qgl = qbase + q;
            #pragma unroll
            for (int j = 0; j < 4; ++j) {
                if (st * 32 + lk * 4 + j > qgl)      sv0[j] = -1e30f;
                if (st * 32 + 16 + lk * 4 + j > qgl) sv1[j] = -1e30f;
            }
        }

        float tm = sv0[0];
        #pragma unroll
        for (int j = 1; j < 4; ++j) tm = fmaxf(tm, sv0[j]);
        #pragma unroll
        for (int j = 0; j < 4; ++j) tm = fmaxf(tm, sv1[j]);
        tm = fmaxf(tm, __shfl_xor(tm, 16));
        tm = fmaxf(tm, __shfl_xor(tm, 32));
        float mn = fmaxf(m_run, tm);
        float alpha = __expf(m_run - mn);
        float p0[4], p1[4], ts = 0.f;
        #pragma unroll
        for (int j = 0; j < 4; ++j) {
            p0[j] = __expf(sv0[j] - mn);
            p1[j] = __expf(sv1[j] - mn);
            ts += p0[j] + p1[j];
        }
        ts += __shfl_xor(ts, 16);
        ts += __shfl_xor(ts, 32);
        l_run = l_run * alpha + ts;
        m_run = mn;

        #pragma unroll
        for (int i = 0; i < 16; ++i) {
            o[i][0] *= alpha; o[i][1] *= alpha; o[i][2] *= alpha; o[i][3] *= alpha;
        }

        unsigned c0 = pk2(p0[0], p0[1]), c1 = pk2(p0[2], p0[3]);
        unsigned d0 = pk2(p1[0], p1[1]), d1 = pk2(p1[2], p1[3]);
        int sA = q + 32 * (lk & 1);
        int sB = sA + 16;
        unsigned a0c = __shfl(c0, sA), a1c = __shfl(c1, sA);
        unsigned b0c = __shfl(c0, sB), b1c = __shfl(c1, sB);
        unsigned a0d = __shfl(d0, sA), a1d = __shfl(d1, sA);
        unsigned b0d = __shfl(d0, sB), b1d = __shfl(d1, sB);
        bool hi = (lk >> 1) != 0;
        union { short8 s; unsigned u[4]; } pb;
        pb.u[0] = hi ? a0d : a0c;
        pb.u[1] = hi ? a1d : a1c;
        pb.u[2] = hi ? b0d : b0c;
        pb.u[3] = hi ? b1d : b1c;

        #pragma unroll
        for (int eb = 0; eb < 16; ++eb) {
            int er = eb * 16 + q;
            int sl = lk ^ (er & 3);
            short8 vf = *(const short8*)&V_s[er * 32 + sl * 8];
            o[eb] = __builtin_amdgcn_mfma_f32_16x16x32_bf16(vf, pb.s, o[eb], 0, 0, 0);
        }
    }

    float inv_l = 1.f / l_run;
    ushort* orow = ao + (size_t)(b * TSEQ + qbase + q) * EMB;
    #pragma unroll
    for (int eb = 0; eb < 16; ++eb) {
        uint2 w;
        w.x = pk2(o[eb][0] * inv_l, o[eb][1] * inv_l);
        w.y = pk2(o[eb][2] * inv_l, o[eb][3] * inv_l);
        *(uint2*)&orow[eb * 16 + lk * 4] = w;
    }
}

// ---------------- logits GEMM (2-phase pipelined) + fused LSE partials ----------------
__global__ __launch_bounds__(256) void k_gemm(const ushort* __restrict__ A,
                                              const ushort* __restrict__ Bt,
                                              const float* __restrict__ lmb,
                                              float* __restrict__ C,
                                              float2* __restrict__ part) {
    __shared__ ushort As[2][128 * 64];
    __shared__ ushort Bs[2][128 * 64];

    int linear = blockIdx.x;
    int swz = (linear & 7) * 1000 + (linear >> 3);   // bijective XCD swizzle (8000%8==0)
    int m0 = (swz & 31) * 128;
    int nb = swz >> 5;
    int n0 = nb * 128;

    int tid = threadIdx.x;
    int lane = tid & 63, wave = tid >> 6;
    int wm = wave >> 1, wn = wave & 1;
    int lr = lane >> 3, cc = lane & 7;
    int lrow = lane & 15, lk = lane >> 4;

    f32x4 acc[4][4];
    #pragma unroll
    for (int i = 0; i < 4; ++i)
        #pragma unroll
        for (int j = 0; j < 4; ++j)
            acc[i][j] = (f32x4){0.f, 0.f, 0.f, 0.f};

    auto STAGE = [&](int buf, int k0) {
        #pragma unroll
        for (int j = 0; j < 4; ++j) {
            int rbase = j * 32 + wave * 8;
            int row = rbase + lr;
            int cs = cc ^ (row & 7);
            const ushort* ga = A + (size_t)(m0 + row) * EMB + k0 + cs * 8;
            const ushort* gb = Bt + (size_t)(n0 + row) * EMB + k0 + cs * 8;
            __builtin_amdgcn_global_load_lds(
                (const __attribute__((address_space(1))) void*)ga,
                (__attribute__((address_space(3))) void*)&As[buf][rbase * 64], 16, 0, 0);
            __builtin_amdgcn_global_load_lds(
                (const __attribute__((address_space(1))) void*)gb,
                (__attribute__((address_space(3))) void*)&Bs[buf][rbase * 64], 16, 0, 0);
        }
    };

    STAGE(0, 0);
    asm volatile("s_waitcnt vmcnt(0)" ::: "memory");
    __syncthreads();

    #pragma unroll
    for (int t = 0; t < 4; ++t) {
        if (t < 3) STAGE((t + 1) & 1, (t + 1) * 64);   // prefetch next, stays in flight under compute
        const ushort* Ab = As[t & 1];
        const ushort* Bb = Bs[t & 1];
        #pragma unroll
        for (int kk = 0; kk < 2; ++kk) {
            short8 a[4], b[4];
            #pragma unroll
            for (int m = 0; m < 4; ++m) {
                int row = wm * 64 + m * 16 + lrow;
                int c2 = (kk * 4 + lk) ^ (row & 7);
                a[m] = *(const short8*)&Ab[row * 64 + c2 * 8];
            }
            #pragma unroll
            for (int n = 0; n < 4; ++n) {
                int row = wn * 64 + n * 16 + lrow;
                int c2 = (kk * 4 + lk) ^ (row & 7);
                b[n] = *(const short8*)&Bb[row * 64 + c2 * 8];
            }
            #pragma unroll
            for (int m = 0; m < 4; ++m)
                #pragma unroll
                for (int n = 0; n < 4; ++n)
                    acc[m][n] = __builtin_amdgcn_mfma_f32_16x16x32_bf16(
                        a[m], b[n], acc[m][n], 0, 0, 0);
        }
        if (t < 3) {
            asm volatile("s_waitcnt vmcnt(0)" ::: "memory");
            __syncthreads();
        }
    }

    float biasv[4];
    #pragma unroll
    for (int n = 0; n < 4; ++n)
        biasv[n] = lmb[n0 + wn * 64 + n * 16 + lrow];

    // write logits (nontemporal: don't thrash L2 which holds Wt panel)
    #pragma unroll
    for (int n = 0; n < 4; ++n) {
        int col = n0 + wn * 64 + n * 16 + lrow;
        #pragma unroll
        for (int m = 0; m < 4; ++m) {
            int rbase = m0 + wm * 64 + m * 16 + lk * 4;
            #pragma unroll
            for (int j = 0; j < 4; ++j)
                __builtin_nontemporal_store(acc[m][n][j] + biasv[n],
                                            &C[(size_t)(rbase + j) * VOCAB + col]);
        }
    }

    // per-row logsumexp partial over this block's 128 cols (overlaps store drain)
    float pM[4][4], pS[4][4];
    #pragma unroll
    for (int m = 0; m < 4; ++m) {
        #pragma unroll
        for (int j = 0; j < 4; ++j) {
            float v0 = acc[m][0][j] + biasv[0];
            float v1 = acc[m][1][j] + biasv[1];
            float v2 = acc[m][2][j] + biasv[2];
            float v3 = acc[m][3][j] + biasv[3];
            float tM = fmaxf(fmaxf(v0, v1), fmaxf(v2, v3));
            float tS = __expf(v0 - tM) + __expf(v1 - tM) + __expf(v2 - tM) + __expf(v3 - tM);
            #pragma unroll
            for (int off = 1; off < 16; off <<= 1) {
                float oM = __shfl_xor(tM, off);
                float oS = __shfl_xor(tS, off);
                float nM = fmaxf(tM, oM);
                tS = tS * __expf(tM - nM) + oS * __expf(oM - nM);
                tM = nM;
            }
            pM[m][j] = tM; pS[m][j] = tS;
        }
    }
    // combine the two n-wave halves via LDS buf0 of As (last read at t=2; all waves
    // passed the t=2 barrier => safe). Raw barrier + lgkmcnt only: C-stores stay in flight.
    float* fb = (float*)&As[0][0];
    if (wn == 0 && lrow == 0) {
        #pragma unroll
        for (int m = 0; m < 4; ++m)
            #pragma unroll
            for (int j = 0; j < 4; ++j) {
                int r64 = m * 16 + lk * 4 + j;
                fb[wm * 64 + r64] = pM[m][j];
                fb[128 + wm * 64 + r64] = pS[m][j];
            }
    }
    asm volatile("s_waitcnt lgkmcnt(0)" ::: "memory");
    __builtin_amdgcn_s_barrier();
    asm volatile("" ::: "memory");
    if (wn == 1 && lrow == 0) {
        #pragma unroll
        for (int m = 0; m < 4; ++m)
            #pragma unroll
            for (int j = 0; j < 4; ++j) {
                int r64 = m * 16 + lk * 4 + j;
                float oM = fb[wm * 64 + r64];
                float oS = fb[128 + wm * 64 + r64];
                float tM = pM[m][j], tS = pS[m][j];
                float nM = fmaxf(tM, oM);
                float nS = tS * __expf(tM - nM) + oS * __expf(oM - nM);
                part[(size_t)(m0 + wm * 64 + r64) * NBLKN + nb] = make_float2(nM, nS);
            }
    }
}

// ---------------- loss reduce over partials ----------------
__global__ __launch_bounds__(256) void k_reduce(const float2* __restrict__ part,
                                                const float* __restrict__ logits,
                                                const int* __restrict__ tgt,
                                                float* __restrict__ loss) {
    int row = blockIdx.x;
    int tid = threadIdx.x;
    float M = -1e30f, S = 0.f;
    for (int i = tid; i < NBLKN; i += 256) {
        float2 p = part[(size_t)row * NBLKN + i];
        float nM = fmaxf(M, p.x);
        S = S * __expf(M - nM) + p.y * __expf(p.x - nM);
        M = nM;
    }
    #pragma unroll
    for (int off = 1; off < 64; off <<= 1) {
        float oM = __shfl_xor(M, off);
        float oS = __shfl_xor(S, off);
        float nM = fmaxf(M, oM);
        S = S * __expf(M - nM) + oS * __expf(oM - nM);
        M = nM;
    }
    __shared__ float wm[4], ws[4];
    int lane = tid & 63, wave = tid >> 6;
    if (lane == 0) { wm[wave] = M; ws[wave] = S; }
    __syncthreads();
    if (tid == 0) {
        float fM = wm[0], fS = ws[0];
        #pragma unroll
        for (int w = 1; w < 4; ++w) {
            float nM = fmaxf(fM, wm[w]);
            fS = fS * __expf(fM - nM) + ws[w] * __expf(wm[w] - nM);
            fM = nM;
        }
        float lse = fM + __logf(fS);
        float tl = logits[(size_t)row * VOCAB + tgt[row]];
        atomicAdd(loss, (lse - tl) * (1.0f / 4096.0f));
    }
}

extern "C" void kernel_launch(void* const* d_in, const int* in_sizes, int n_in,
                              void* d_out, int out_size, void* d_ws, size_t ws_size,
                              hipStream_t stream) {
    (void)in_sizes; (void)n_in; (void)ws_size;
    const int*   idx     = (const int*)d_in[0];
    const int*   targets = (const int*)d_in[1];
    const float* tok     = (const float*)d_in[2];
    const float* pos     = (const float*)d_in[3];
    const float* Wk      = (const float*)d_in[4];
    const float* Wq      = (const float*)d_in[5];
    const float* Wv      = (const float*)d_in[6];
    const float* lmW     = (const float*)d_in[7];
    const float* lmb     = (const float*)d_in[8];

    float* logits = (float*)d_out;
    float* loss   = logits + (size_t)out_size - 1;

    const size_t MB = 1u << 20;
    char* w = (char*)d_ws;
    ushort* Wt3  = (ushort*)(w);                 // 384 KB
    ushort* xb   = (ushort*)(w + MB / 2);        // 2 MB
    ushort* qb   = (ushort*)(w + 5 * MB / 2);    // 2 MB
    ushort* kbf  = (ushort*)(w + 9 * MB / 2);    // 2 MB
    ushort* vb   = (ushort*)(w + 13 * MB / 2);   // 2 MB
    ushort* vt   = (ushort*)(w + 17 * MB / 2);   // 2 MB
    ushort* ao   = (ushort*)(w + 21 * MB / 2);   // 2 MB
    ushort* Wt   = (ushort*)(w + 25 * MB / 2);   // 16 MB
    float2* part = (float2*)(w + 57 * MB / 2);   // 7.9 MB

    k_convW<<<dim3(VOCAB / 32, EMB / 32), 256, 0, stream>>>(lmW, Wt);
    k_convw3<<<dim3(8, 8, 3), 256, 0, stream>>>(Wq, Wk, Wv, Wt3);
    k_embed<<<NROWS, 256, 0, stream>>>(idx, tok, pos, xb);
    k_qkv_mm<<<dim3(NROWS / 128, EMB / 128, 3), 256, 0, stream>>>(xb, Wt3, qb, kbf, vb);
    k_vt<<<dim3(NROWS / 32, EMB / 32), 256, 0, stream>>>(vb, vt);
    k_attn<<<256, 64, 0, stream>>>(qb, kbf, vt, ao);
    k_gemm<<<8000, 256, 0, stream>>>(ao, Wt, lmb, logits, part);
    hipMemsetAsync(loss, 0, sizeof(float), stream);
    k_reduce<<<NROWS, 256, 0, stream>>>(part, logits, targets, loss);
}